// Round 7
// baseline (1124.325 us; speedup 1.0000x reference)
//
#include <hip/hip_runtime.h>
#include <stdint.h>
#include <math.h>

// Problem constants: B=2, H=16, S=2048, D=64
#define BB 2
#define HH 16
#define SS 2048
#define DD 64
#define QE  ((size_t)BB * HH * SS * DD)  // elements per tensor
#define PME ((size_t)BB * SS * SS)       // packed-mask elements (uint16)

#define WROW 36                          // W row stride in DWORDS (32 + 4 pad; 144 B keeps 16B align)

typedef __attribute__((ext_vector_type(8))) short short8;   // bf16x8 MFMA frag
typedef __attribute__((ext_vector_type(4))) float float4v;  // fp32x4 accum

__device__ __forceinline__ float bflo(unsigned int u){ return __uint_as_float(u << 16); }
__device__ __forceinline__ float bfhi(unsigned int u){ return __uint_as_float(u & 0xffff0000u); }
__device__ __forceinline__ unsigned short f2bf(float f){
  unsigned int u = __float_as_uint(f);
  u += 0x7fffu + ((u >> 16) & 1u);   // RNE
  return (unsigned short)(u >> 16);
}
__device__ __forceinline__ unsigned int pk2(float lo, float hi){
  return ((unsigned int)f2bf(hi) << 16) | (unsigned int)f2bf(lo);
}

// ---------------------------------------------------------------------------
// Mask dtype detection (verified rounds 0-6).
// ---------------------------------------------------------------------------
__global__ void detect_mask_mode(const unsigned int* __restrict__ mw, int* __restrict__ mode_out){
  __shared__ int a32, af, a64;
  const int t = threadIdx.x;
  if (t == 0){ a32 = 1; af = 1; a64 = 1; }
  __syncthreads();
  int ok32 = 1, okf = 1, ok64 = 1;
  for (int idx = t; idx < 4096; idx += 256){
    const unsigned int w = mw[idx];
    if (w > 1u) ok32 = 0;
    if (w != 0u && w != 0x3F800000u) okf = 0;
    if ((idx & 1) ? (w != 0u) : (w > 1u)) ok64 = 0;
  }
  if (!ok32) atomicAnd(&a32, 0);
  if (!okf)  atomicAnd(&af, 0);
  if (!ok64) atomicAnd(&a64, 0);
  __syncthreads();
  if (t == 0){
    int mode;
    if (a64)      mode = 3;
    else if (a32) mode = 0;
    else if (af)  mode = 2;
    else          mode = 1;
    *mode_out = mode;
  }
}

// ---------------------------------------------------------------------------
// Pack mask[b][h][q][k] -> pm[b][q][k] uint16 (bit h set if masked).
// (verified round 3)
// ---------------------------------------------------------------------------
__global__ __launch_bounds__(256) void pack_mask_kernel(
    const void* __restrict__ mask, const int* __restrict__ modep,
    unsigned short* __restrict__ pm)
{
  const int mode = *modep;
  const size_t tid  = (size_t)blockIdx.x * 256 + threadIdx.x;
  const size_t base = tid * 8;
  const size_t bq   = base >> 11;
  const int    k0   = (int)(base & (SS - 1));
  const size_t b    = bq >> 11;
  const size_t q    = bq & (SS - 1);

  unsigned short outv[8] = {0,0,0,0,0,0,0,0};

  if (mode == 0 || mode == 2){
    const unsigned int* p = (const unsigned int*)mask;
    #pragma unroll
    for (int h = 0; h < HH; ++h){
      const size_t e = ((b * HH + h) * SS + q) * SS + k0;
      const uint4 a = *(const uint4*)(p + e);
      const uint4 c = *(const uint4*)(p + e + 4);
      const unsigned short bit = (unsigned short)(1u << h);
      if (a.x) outv[0] |= bit;  if (a.y) outv[1] |= bit;
      if (a.z) outv[2] |= bit;  if (a.w) outv[3] |= bit;
      if (c.x) outv[4] |= bit;  if (c.y) outv[5] |= bit;
      if (c.z) outv[6] |= bit;  if (c.w) outv[7] |= bit;
    }
  } else if (mode == 1){
    const unsigned char* p = (const unsigned char*)mask;
    #pragma unroll
    for (int h = 0; h < HH; ++h){
      const size_t e = ((b * HH + h) * SS + q) * SS + k0;
      uint2 a = *(const uint2*)(p + e);
      const unsigned short bit = (unsigned short)(1u << h);
      #pragma unroll
      for (int j = 0; j < 4; ++j){
        if ((a.x >> (8*j)) & 0xffu) outv[j]     |= bit;
        if ((a.y >> (8*j)) & 0xffu) outv[4 + j] |= bit;
      }
    }
  } else {
    const unsigned int* p = (const unsigned int*)mask;
    #pragma unroll
    for (int h = 0; h < HH; ++h){
      const size_t e = (((b * HH + h) * SS + q) * SS + k0) * 2;
      const unsigned short bit = (unsigned short)(1u << h);
      #pragma unroll
      for (int j = 0; j < 4; ++j){
        const uint4 a = *(const uint4*)(p + e + j * 4);
        if (a.x) outv[j * 2]     |= bit;
        if (a.z) outv[j * 2 + 1] |= bit;
      }
    }
  }

  uint4 w;
  w.x = (unsigned int)outv[0] | ((unsigned int)outv[1] << 16);
  w.y = (unsigned int)outv[2] | ((unsigned int)outv[3] << 16);
  w.z = (unsigned int)outv[4] | ((unsigned int)outv[5] << 16);
  w.w = (unsigned int)outv[6] | ((unsigned int)outv[7] << 16);
  *(uint4*)(pm + base) = w;
}

// ---------------------------------------------------------------------------
// Prep: fp32 -> bf16 (scale folded for Q)
// ---------------------------------------------------------------------------
__global__ void conv_bf16_kernel(const float* __restrict__ src, unsigned short* __restrict__ dst, float scale){
  const size_t i = ((size_t)blockIdx.x * 256 + threadIdx.x) * 8;
  const float4 a = *(const float4*)(src + i);
  const float4 b = *(const float4*)(src + i + 4);
  uint4 o;
  o.x = pk2(a.x * scale, a.y * scale);
  o.y = pk2(a.z * scale, a.w * scale);
  o.z = pk2(b.x * scale, b.y * scale);
  o.w = pk2(b.z * scale, b.w * scale);
  *(uint4*)(dst + i) = o;
}

// ---------------------------------------------------------------------------
// Prep: V[b,h,k,d] fp32 -> Vt[b,h,d,k] bf16 (verified round 1)
// ---------------------------------------------------------------------------
__global__ void transp_v_kernel(const float* __restrict__ V, unsigned short* __restrict__ Vt){
  __shared__ unsigned short tile[64][66];
  const int t  = threadIdx.x;
  const int kt = blockIdx.x & 31;
  const int bh = blockIdx.x >> 5;
  {
    const int kr = t >> 2, dc = (t & 3) * 16;
    const float* src = V + ((size_t)bh * SS + (size_t)(kt * 64 + kr)) * DD + dc;
    #pragma unroll
    for (int c = 0; c < 4; ++c){
      const float4 v = *(const float4*)(src + c * 4);
      tile[kr][dc + c * 4 + 0] = f2bf(v.x);
      tile[kr][dc + c * 4 + 1] = f2bf(v.y);
      tile[kr][dc + c * 4 + 2] = f2bf(v.z);
      tile[kr][dc + c * 4 + 3] = f2bf(v.w);
    }
  }
  __syncthreads();
  {
    const int dr = t >> 2, kc = (t & 3) * 16;
    unsigned short* dst = Vt + ((size_t)bh * DD + dr) * SS + kt * 64 + kc;
    unsigned int w[8];
    #pragma unroll
    for (int p = 0; p < 8; ++p){
      w[p] = (unsigned int)tile[kc + 2*p][dr] | ((unsigned int)tile[kc + 2*p + 1][dr] << 16);
    }
    uint4 o0 = { w[0], w[1], w[2], w[3] };
    uint4 o1 = { w[4], w[5], w[6], w[7] };
    *(uint4*)(dst)     = o0;
    *(uint4*)(dst + 8) = o1;
  }
}

// ---------------------------------------------------------------------------
// Main fused kernel — small-block / high-block-count retile:
//  * Block = 128 thr (2 waves), k-step 32, split-k=4 -> 1024 blocks = 4/CU
//    (vs round 6's 1/CU): 4 independent blocks interleave on each CU; barrier
//    groups are 2 waves. __launch_bounds__(128,2) -> VGPR<=256 (no 128-cap
//    spills; O accum alone is 128).
//  * W double-buffered, packed head-pair dword layout Wp[hp][q][WROW=36 dw]
//    (value dword = (bf16 w[2hp], bf16 w[2hp+1])): softmax writes are 32x
//    ds_write_b32 (2-way banks = free), PV reads 2x ds_read_b128 per head-
//    pair + in-lane lo/hi split. 2 x 18 KB = 36 KB LDS.
//  * Score: wave w scores keys w*16..w*16+15 for ALL 16 heads (in-lane
//    softmax over h, verified since round 1); chunks of 2 heads.
//  * PV: wave w owns heads 8w..8w+7; one K=32 MFMA per (head, d-tile).
//  * Single barrier per k-step (W dbuf bounds run-ahead, verified round 6).
//  * XCD swizzle: L&7 = (b,kc) -> each (b,kc)'s 4 MB K+Vt chunk pinned to
//    one XCD's L2 (round-6-verified: FETCH 645->51 MB).
// ---------------------------------------------------------------------------
__global__ __launch_bounds__(128, 2) void attn_main_kernel(
    const unsigned short* __restrict__ Qb, const unsigned short* __restrict__ Kb,
    const unsigned short* __restrict__ Vt, const unsigned short* __restrict__ pm,
    float* __restrict__ out)
{
  __shared__ unsigned int Wp[2][8 * 16 * WROW];   // 2 x 18432 B

  const int t = threadIdx.x;
  const int wave = t >> 6, lane = t & 63, quad = lane >> 4, l16 = lane & 15;

  const int L  = blockIdx.x;
  const int kc = L & 3;
  const int b  = (L >> 2) & 1;
  const int q0 = (L >> 3) << 4;

  float4v O[8][4];   // [head-within-wave][d-tile] = 128 VGPR
  #pragma unroll
  for (int i = 0; i < 8; ++i)
    #pragma unroll
    for (int j = 0; j < 4; ++j) O[i][j] = (float4v){0.f, 0.f, 0.f, 0.f};

  const unsigned short* qbase = Qb + ((size_t)(b * HH) * SS + (size_t)(q0 + l16)) * DD + quad * 8;
  const unsigned short* kbas0 = Kb + ((size_t)(b * HH) * SS + (size_t)(kc * 512 + wave * 16 + l16)) * DD + quad * 8;
  const unsigned short* pmrow = pm + ((size_t)b * SS + (size_t)(q0 + quad * 4)) * SS + (size_t)(kc * 512 + wave * 16 + l16);

  // mask prefetch for ks=0
  unsigned int m16[4];
  #pragma unroll
  for (int r = 0; r < 4; ++r) m16[r] = (unsigned int)pmrow[(size_t)r * SS];

  #pragma unroll 1
  for (int ks = 0; ks < 16; ++ks){
    const int k0 = kc * 512 + ks * 32;

    // ---- scores: all 16 heads for this wave's 16-key sub-tile; chunks of 2 ----
    unsigned int sp[HH][2];
    const unsigned short* kbase = kbas0 + (size_t)ks * 32 * DD;

    #pragma unroll
    for (int ch = 0; ch < 8; ++ch){
      short8 qa0[2], qa1[2], kb0[2], kb1[2];
      #pragma unroll
      for (int j = 0; j < 2; ++j){
        const int h = ch * 2 + j;
        const unsigned short* qp = qbase + (size_t)h * (SS * DD);
        const unsigned short* kp = kbase + (size_t)h * (SS * DD);
        qa0[j] = *(const short8*)(qp);
        qa1[j] = *(const short8*)(qp + 32);
        kb0[j] = *(const short8*)(kp);
        kb1[j] = *(const short8*)(kp + 32);
      }
      #pragma unroll
      for (int j = 0; j < 2; ++j){
        const int h = ch * 2 + j;
        float4v c = (float4v){0.f, 0.f, 0.f, 0.f};
        c = __builtin_amdgcn_mfma_f32_16x16x32_bf16(qa0[j], kb0[j], c, 0, 0, 0);
        c = __builtin_amdgcn_mfma_f32_16x16x32_bf16(qa1[j], kb1[j], c, 0, 0, 0);
        #pragma unroll
        for (int r = 0; r < 4; ++r) if ((m16[r] >> h) & 1u) c[r] = -INFINITY;
        sp[h][0] = pk2(c[0], c[1]);
        sp[h][1] = pk2(c[2], c[3]);
      }
    }

    // ---- prefetch next step's mask words ----
    if (ks < 15){
      #pragma unroll
      for (int r = 0; r < 4; ++r) m16[r] = (unsigned int)pmrow[(size_t)r * SS + (size_t)(ks + 1) * 32];
    }

    // ---- in-lane softmax over heads; packed head-pair dword writes ----
    unsigned int* Wc = &Wp[ks & 1][0];
    const int kdx = wave * 16 + l16;
    #pragma unroll
    for (int r = 0; r < 4; ++r){
      const int row = quad * 4 + r;
      float sv[HH];
      float m = -INFINITY;
      #pragma unroll
      for (int h = 0; h < HH; ++h){
        const unsigned int u = sp[h][r >> 1];
        const float f = (r & 1) ? bfhi(u) : bflo(u);
        sv[h] = f;
        m = fmaxf(m, f);
      }
      float sum = 0.f;
      #pragma unroll
      for (int h = 0; h < HH; ++h){
        const float e = (sv[h] != -INFINITY) ? __expf(sv[h] - m) : 0.f;
        sv[h] = e;
        sum += e;
      }
      const float rinv = (sum > 0.f) ? (1.0f / sum) : 0.f;
      #pragma unroll
      for (int hp = 0; hp < 8; ++hp){
        Wc[hp * (16 * WROW) + row * WROW + kdx] = pk2(sv[2 * hp] * rinv, sv[2 * hp + 1] * rinv);
      }
    }
    __syncthreads();

    // ---- PV: this wave owns head-pairs 4w..4w+3 (heads 8w..8w+7) ----
    #pragma unroll
    for (int hp2 = 0; hp2 < 4; ++hp2){
      const int hp = wave * 4 + hp2;
      const unsigned int* wb = &Wc[hp * (16 * WROW) + l16 * WROW + quad * 8];
      const uint4 da = *(const uint4*)(wb);
      const uint4 db = *(const uint4*)(wb + 4);
      const unsigned int d0 = da.x, d1 = da.y, d2 = da.z, d3 = da.w;
      const unsigned int d4 = db.x, d5 = db.y, d6 = db.z, d7 = db.w;
      uint4 ue, uo;
      ue.x = (d0 & 0xffffu) | (d1 << 16);
      ue.y = (d2 & 0xffffu) | (d3 << 16);
      ue.z = (d4 & 0xffffu) | (d5 << 16);
      ue.w = (d6 & 0xffffu) | (d7 << 16);
      uo.x = (d0 >> 16) | (d1 & 0xffff0000u);
      uo.y = (d2 >> 16) | (d3 & 0xffff0000u);
      uo.z = (d4 >> 16) | (d5 & 0xffff0000u);
      uo.w = (d6 >> 16) | (d7 & 0xffff0000u);
      const short8 ae = __builtin_bit_cast(short8, ue);
      const short8 ao = __builtin_bit_cast(short8, uo);

      const unsigned short* ve = Vt + ((size_t)(b * HH + 2 * hp) * DD + l16) * SS + k0 + quad * 8;
      const unsigned short* vo = ve + (size_t)SS * DD;
      #pragma unroll
      for (int dt = 0; dt < 4; ++dt){
        const short8 bve = *(const short8*)(ve + (size_t)dt * 16 * SS);
        const short8 bvo = *(const short8*)(vo + (size_t)dt * 16 * SS);
        O[hp2 * 2 + 0][dt] = __builtin_amdgcn_mfma_f32_16x16x32_bf16(ae, bve, O[hp2 * 2 + 0][dt], 0, 0, 0);
        O[hp2 * 2 + 1][dt] = __builtin_amdgcn_mfma_f32_16x16x32_bf16(ao, bvo, O[hp2 * 2 + 1][dt], 0, 0, 0);
      }
    }
    // no second barrier: W double-buffered; run-ahead bounded by barrier ks+1
  }

  // ---- epilogue: atomic accumulate split-k partials ----
  #pragma unroll
  for (int hh = 0; hh < 8; ++hh){
    const int h = wave * 8 + hh;
    #pragma unroll
    for (int dt = 0; dt < 4; ++dt){
      #pragma unroll
      for (int r = 0; r < 4; ++r){
        float* op = out + (((size_t)b * SS + (size_t)(q0 + quad * 4 + r)) * HH + h) * DD + dt * 16 + l16;
        unsafeAtomicAdd(op, O[hh][dt][r]);
      }
    }
  }
}

extern "C" void kernel_launch(void* const* d_in, const int* in_sizes, int n_in,
                              void* d_out, int out_size, void* d_ws, size_t ws_size,
                              hipStream_t stream)
{
  const float* Q = (const float*)d_in[0];
  const float* K = (const float*)d_in[1];
  const float* V = (const float*)d_in[2];
  const void* mask = d_in[3];

  uintptr_t base = (uintptr_t)d_ws;
  int* mode_ptr       = (int*)base;
  unsigned short* Qb  = (unsigned short*)(base + 64);
  unsigned short* Kb  = Qb + QE;
  unsigned short* Vt  = Kb + QE;
  unsigned short* pmp = Vt + QE;                 // 16.8 MB packed mask

  detect_mask_mode<<<1, 256, 0, stream>>>((const unsigned int*)mask, mode_ptr);
  pack_mask_kernel<<<(int)(PME / (256 * 8)), 256, 0, stream>>>(mask, mode_ptr, pmp);
  conv_bf16_kernel<<<2048, 256, 0, stream>>>(Q, Qb, 0.125f);
  conv_bf16_kernel<<<2048, 256, 0, stream>>>(K, Kb, 1.0f);
  transp_v_kernel<<<BB * HH * (SS / 64), 256, 0, stream>>>(V, Vt);
  hipMemsetAsync(d_out, 0, (size_t)out_size * sizeof(float), stream);

  attn_main_kernel<<<1024, 128, 0, stream>>>(Qb, Kb, Vt, pmp, (float*)d_out);
}

// Round 8
// 1017.368 us; speedup vs baseline: 1.1051x; 1.1051x over previous
//
#include <hip/hip_runtime.h>
#include <stdint.h>
#include <math.h>

// Problem constants: B=2, H=16, S=2048, D=64
#define BB 2
#define HH 16
#define SS 2048
#define DD 64
#define QE  ((size_t)BB * HH * SS * DD)  // elements per tensor
#define PME ((size_t)BB * SS * SS)       // packed-mask elements (uint16)

#define WROW 36                          // W row stride in DWORDS (32 + 4 pad)

typedef __attribute__((ext_vector_type(8))) short short8;   // bf16x8 MFMA frag
typedef __attribute__((ext_vector_type(4))) float float4v;  // fp32x4 accum

__device__ __forceinline__ float bflo(unsigned int u){ return __uint_as_float(u << 16); }
__device__ __forceinline__ float bfhi(unsigned int u){ return __uint_as_float(u & 0xffff0000u); }
__device__ __forceinline__ unsigned short f2bf(float f){
  unsigned int u = __float_as_uint(f);
  u += 0x7fffu + ((u >> 16) & 1u);   // RNE
  return (unsigned short)(u >> 16);
}
__device__ __forceinline__ unsigned int pk2(float lo, float hi){
  return ((unsigned int)f2bf(hi) << 16) | (unsigned int)f2bf(lo);
}

// ---------------------------------------------------------------------------
// Mask dtype detection (verified rounds 0-7).
// ---------------------------------------------------------------------------
__global__ void detect_mask_mode(const unsigned int* __restrict__ mw, int* __restrict__ mode_out){
  __shared__ int a32, af, a64;
  const int t = threadIdx.x;
  if (t == 0){ a32 = 1; af = 1; a64 = 1; }
  __syncthreads();
  int ok32 = 1, okf = 1, ok64 = 1;
  for (int idx = t; idx < 4096; idx += 256){
    const unsigned int w = mw[idx];
    if (w > 1u) ok32 = 0;
    if (w != 0u && w != 0x3F800000u) okf = 0;
    if ((idx & 1) ? (w != 0u) : (w > 1u)) ok64 = 0;
  }
  if (!ok32) atomicAnd(&a32, 0);
  if (!okf)  atomicAnd(&af, 0);
  if (!ok64) atomicAnd(&a64, 0);
  __syncthreads();
  if (t == 0){
    int mode;
    if (a64)      mode = 3;
    else if (a32) mode = 0;
    else if (af)  mode = 2;
    else          mode = 1;
    *mode_out = mode;
  }
}

// ---------------------------------------------------------------------------
// Pack mask[b][h][q][k] -> pm[b][q][k] uint16 (bit h set if masked).
// (verified round 3)
// ---------------------------------------------------------------------------
__global__ __launch_bounds__(256) void pack_mask_kernel(
    const void* __restrict__ mask, const int* __restrict__ modep,
    unsigned short* __restrict__ pm)
{
  const int mode = *modep;
  const size_t tid  = (size_t)blockIdx.x * 256 + threadIdx.x;
  const size_t base = tid * 8;
  const size_t bq   = base >> 11;
  const int    k0   = (int)(base & (SS - 1));
  const size_t b    = bq >> 11;
  const size_t q    = bq & (SS - 1);

  unsigned short outv[8] = {0,0,0,0,0,0,0,0};

  if (mode == 0 || mode == 2){
    const unsigned int* p = (const unsigned int*)mask;
    #pragma unroll
    for (int h = 0; h < HH; ++h){
      const size_t e = ((b * HH + h) * SS + q) * SS + k0;
      const uint4 a = *(const uint4*)(p + e);
      const uint4 c = *(const uint4*)(p + e + 4);
      const unsigned short bit = (unsigned short)(1u << h);
      if (a.x) outv[0] |= bit;  if (a.y) outv[1] |= bit;
      if (a.z) outv[2] |= bit;  if (a.w) outv[3] |= bit;
      if (c.x) outv[4] |= bit;  if (c.y) outv[5] |= bit;
      if (c.z) outv[6] |= bit;  if (c.w) outv[7] |= bit;
    }
  } else if (mode == 1){
    const unsigned char* p = (const unsigned char*)mask;
    #pragma unroll
    for (int h = 0; h < HH; ++h){
      const size_t e = ((b * HH + h) * SS + q) * SS + k0;
      uint2 a = *(const uint2*)(p + e);
      const unsigned short bit = (unsigned short)(1u << h);
      #pragma unroll
      for (int j = 0; j < 4; ++j){
        if ((a.x >> (8*j)) & 0xffu) outv[j]     |= bit;
        if ((a.y >> (8*j)) & 0xffu) outv[4 + j] |= bit;
      }
    }
  } else {
    const unsigned int* p = (const unsigned int*)mask;
    #pragma unroll
    for (int h = 0; h < HH; ++h){
      const size_t e = (((b * HH + h) * SS + q) * SS + k0) * 2;
      const unsigned short bit = (unsigned short)(1u << h);
      #pragma unroll
      for (int j = 0; j < 4; ++j){
        const uint4 a = *(const uint4*)(p + e + j * 4);
        if (a.x) outv[j * 2]     |= bit;
        if (a.z) outv[j * 2 + 1] |= bit;
      }
    }
  }

  uint4 w;
  w.x = (unsigned int)outv[0] | ((unsigned int)outv[1] << 16);
  w.y = (unsigned int)outv[2] | ((unsigned int)outv[3] << 16);
  w.z = (unsigned int)outv[4] | ((unsigned int)outv[5] << 16);
  w.w = (unsigned int)outv[6] | ((unsigned int)outv[7] << 16);
  *(uint4*)(pm + base) = w;
}

// ---------------------------------------------------------------------------
// Prep: fp32 -> bf16 (scale folded for Q)
// ---------------------------------------------------------------------------
__global__ void conv_bf16_kernel(const float* __restrict__ src, unsigned short* __restrict__ dst, float scale){
  const size_t i = ((size_t)blockIdx.x * 256 + threadIdx.x) * 8;
  const float4 a = *(const float4*)(src + i);
  const float4 b = *(const float4*)(src + i + 4);
  uint4 o;
  o.x = pk2(a.x * scale, a.y * scale);
  o.y = pk2(a.z * scale, a.w * scale);
  o.z = pk2(b.x * scale, b.y * scale);
  o.w = pk2(b.z * scale, b.w * scale);
  *(uint4*)(dst + i) = o;
}

// ---------------------------------------------------------------------------
// Prep: V[b,h,k,d] fp32 -> Vt[b,h,d,k] bf16 (verified round 1)
// ---------------------------------------------------------------------------
__global__ void transp_v_kernel(const float* __restrict__ V, unsigned short* __restrict__ Vt){
  __shared__ unsigned short tile[64][66];
  const int t  = threadIdx.x;
  const int kt = blockIdx.x & 31;
  const int bh = blockIdx.x >> 5;
  {
    const int kr = t >> 2, dc = (t & 3) * 16;
    const float* src = V + ((size_t)bh * SS + (size_t)(kt * 64 + kr)) * DD + dc;
    #pragma unroll
    for (int c = 0; c < 4; ++c){
      const float4 v = *(const float4*)(src + c * 4);
      tile[kr][dc + c * 4 + 0] = f2bf(v.x);
      tile[kr][dc + c * 4 + 1] = f2bf(v.y);
      tile[kr][dc + c * 4 + 2] = f2bf(v.z);
      tile[kr][dc + c * 4 + 3] = f2bf(v.w);
    }
  }
  __syncthreads();
  {
    const int dr = t >> 2, kc = (t & 3) * 16;
    unsigned short* dst = Vt + ((size_t)bh * DD + dr) * SS + kt * 64 + kc;
    unsigned int w[8];
    #pragma unroll
    for (int p = 0; p < 8; ++p){
      w[p] = (unsigned int)tile[kc + 2*p][dr] | ((unsigned int)tile[kc + 2*p + 1][dr] << 16);
    }
    uint4 o0 = { w[0], w[1], w[2], w[3] };
    uint4 o1 = { w[4], w[5], w[6], w[7] };
    *(uint4*)(dst)     = o0;
    *(uint4*)(dst + 8) = o1;
  }
}

// ---------------------------------------------------------------------------
// Main fused kernel — PRODUCER/CONSUMER WAVE SPECIALIZATION.
// Block = 256 thr (4 waves). Waves 0-1 = producers, waves 2-3 = consumers.
//  * Q A-frags staged to LDS once (32 KB) -> zero global Q re-reads (round 7's
//    L2-thrash source: 485 MB FETCH from 16x Q re-read at 4 blocks/CU).
//  * Producer p: per 32-key step, scores its 16-key subtile for ALL 16 heads
//    (16x16x32 MFMA, chunks of 4 heads with batched K loads), applies packed
//    mask, in-lane softmax over h (verified since round 1), writes W to the
//    double-buffered packed head-pair tile Wp[2] (2 x 18 KB).
//  * Consumer c: owns heads 8c..8c+7. Issues its Vt loads BEFORE the barrier
//    (independent of W -> latency absorbed by producer softmax), then
//    2x ds_read_b128 per head-pair + in-lane lo/hi split (round-7-verified),
//    one K=32 MFMA per (head, d-tile). Rolling Vt prefetch over head-pairs
//    (round-5-verified pattern).
//  * ONE barrier per k-step; W dbuf bounds run-ahead (verified round 6).
//    Producers and consumers execute equal barrier counts (32 each).
//  * Grid/swizzle = round-6-VERIFIED mapping (split-k=2, 512 blocks, 2/CU,
//    FETCH 51 MB): b=(L>>1)&1, kc=(L>>2)&1, q0 from remaining bits; per-XCD
//    L2 working set = K+Vt chunk (~4 MB) + pm stream, Q exempt (LDS).
// LDS: Qf 32 KB + Wp 36 KB = 69.6 KB -> 2 blocks/CU (8 waves/CU).
// ---------------------------------------------------------------------------
__global__ __launch_bounds__(256, 2) void attn_main_kernel(
    const unsigned short* __restrict__ Qb, const unsigned short* __restrict__ Kb,
    const unsigned short* __restrict__ Vt, const unsigned short* __restrict__ pm,
    float* __restrict__ out)
{
  __shared__ unsigned short Qf[HH * 2 * 512];     // 32768 B: [h][frag][lane*8]
  __shared__ unsigned int  Wp[2][8 * 16 * WROW];  // 2 x 18432 B

  const int t = threadIdx.x;
  const int wave = t >> 6, lane = t & 63, quad = lane >> 4, l16 = lane & 15;

  const int L  = blockIdx.x;
  const int b  = (L >> 1) & 1;
  const int kc = (L >> 2) & 1;
  const int q0 = (((L >> 3) << 1) | (L & 1)) * 16;

  // ---- stage Q A-frags to LDS once (wave w stages heads 4w..4w+3) ----
  #pragma unroll
  for (int hh = 0; hh < 4; ++hh){
    const int h = wave * 4 + hh;
    const unsigned short* qp = Qb + ((size_t)(b * HH + h) * SS + (size_t)(q0 + l16)) * DD + quad * 8;
    *(short8*)&Qf[(h * 2 + 0) * 512 + lane * 8] = *(const short8*)(qp);
    *(short8*)&Qf[(h * 2 + 1) * 512 + lane * 8] = *(const short8*)(qp + 32);
  }
  __syncthreads();

  if (wave < 2){
    // ======================= PRODUCER =======================
    const int p = wave;
    const unsigned short* kbas0 = Kb + ((size_t)(b * HH) * SS + (size_t)(kc * 1024 + p * 16 + l16)) * DD + quad * 8;
    const unsigned short* pmrow = pm + ((size_t)b * SS + (size_t)(q0 + quad * 4)) * SS + (size_t)(kc * 1024 + p * 16 + l16);

    unsigned int m16[4];
    #pragma unroll
    for (int r = 0; r < 4; ++r) m16[r] = (unsigned int)pmrow[(size_t)r * SS];

    #pragma unroll 1
    for (int ks = 0; ks < 32; ++ks){
      // ---- scores: all 16 heads; chunks of 4 with batched K loads ----
      unsigned int sp[HH][2];
      const unsigned short* kbase = kbas0 + (size_t)ks * 32 * DD;

      #pragma unroll
      for (int ch = 0; ch < 4; ++ch){
        short8 kb0[4], kb1[4];
        #pragma unroll
        for (int j = 0; j < 4; ++j){
          const unsigned short* kp = kbase + (size_t)(ch * 4 + j) * (SS * DD);
          kb0[j] = *(const short8*)(kp);
          kb1[j] = *(const short8*)(kp + 32);
        }
        #pragma unroll
        for (int j = 0; j < 4; ++j){
          const int h = ch * 4 + j;
          const short8 a0 = *(const short8*)&Qf[(h * 2 + 0) * 512 + lane * 8];
          const short8 a1 = *(const short8*)&Qf[(h * 2 + 1) * 512 + lane * 8];
          float4v c = (float4v){0.f, 0.f, 0.f, 0.f};
          c = __builtin_amdgcn_mfma_f32_16x16x32_bf16(a0, kb0[j], c, 0, 0, 0);
          c = __builtin_amdgcn_mfma_f32_16x16x32_bf16(a1, kb1[j], c, 0, 0, 0);
          #pragma unroll
          for (int r = 0; r < 4; ++r) if ((m16[r] >> h) & 1u) c[r] = -INFINITY;
          sp[h][0] = pk2(c[0], c[1]);
          sp[h][1] = pk2(c[2], c[3]);
        }
      }

      // ---- prefetch next step's mask words ----
      if (ks < 31){
        #pragma unroll
        for (int r = 0; r < 4; ++r) m16[r] = (unsigned int)pmrow[(size_t)r * SS + (size_t)(ks + 1) * 32];
      }

      // ---- in-lane softmax over heads; packed head-pair dword writes ----
      unsigned int* Wc = &Wp[ks & 1][0];
      const int kdx = p * 16 + l16;
      #pragma unroll
      for (int r = 0; r < 4; ++r){
        const int row = quad * 4 + r;
        float sv[HH];
        float m = -INFINITY;
        #pragma unroll
        for (int h = 0; h < HH; ++h){
          const unsigned int u = sp[h][r >> 1];
          const float f = (r & 1) ? bfhi(u) : bflo(u);
          sv[h] = f;
          m = fmaxf(m, f);
        }
        float sum = 0.f;
        #pragma unroll
        for (int h = 0; h < HH; ++h){
          const float e = (sv[h] != -INFINITY) ? __expf(sv[h] - m) : 0.f;
          sv[h] = e;
          sum += e;
        }
        const float rinv = (sum > 0.f) ? (1.0f / sum) : 0.f;
        #pragma unroll
        for (int hp = 0; hp < 8; ++hp){
          Wc[hp * (16 * WROW) + row * WROW + kdx] = pk2(sv[2 * hp] * rinv, sv[2 * hp + 1] * rinv);
        }
      }
      __syncthreads();
    }
  } else {
    // ======================= CONSUMER =======================
    const int c = wave - 2;                 // owns heads 8c..8c+7 (hp 4c..4c+3)
    float4v O[8][4];                        // [head j = 2*hp2+parity][d-tile]
    #pragma unroll
    for (int i = 0; i < 8; ++i)
      #pragma unroll
      for (int j = 0; j < 4; ++j) O[i][j] = (float4v){0.f, 0.f, 0.f, 0.f};

    #pragma unroll 1
    for (int ks = 0; ks < 32; ++ks){
      const int k0 = kc * 1024 + ks * 32;

      // ---- Vt prefetch for hp2=0 BEFORE the barrier (independent of W) ----
      short8 vb[2][8];   // [buf][head-even dt0..3, head-odd dt0..3]
      {
        const int hp = c * 4;
        const unsigned short* ve = Vt + ((size_t)(b * HH + 2 * hp) * DD + l16) * SS + k0 + quad * 8;
        const unsigned short* vo = ve + (size_t)SS * DD;
        #pragma unroll
        for (int dt = 0; dt < 4; ++dt){
          vb[0][dt]     = *(const short8*)(ve + (size_t)dt * 16 * SS);
          vb[0][4 + dt] = *(const short8*)(vo + (size_t)dt * 16 * SS);
        }
      }
      __syncthreads();

      const unsigned int* Wc = &Wp[ks & 1][0];
      #pragma unroll
      for (int hp2 = 0; hp2 < 4; ++hp2){
        const int cur = hp2 & 1;
        if (hp2 < 3){
          const int hpn = c * 4 + hp2 + 1;
          const unsigned short* ve = Vt + ((size_t)(b * HH + 2 * hpn) * DD + l16) * SS + k0 + quad * 8;
          const unsigned short* vo = ve + (size_t)SS * DD;
          #pragma unroll
          for (int dt = 0; dt < 4; ++dt){
            vb[cur ^ 1][dt]     = *(const short8*)(ve + (size_t)dt * 16 * SS);
            vb[cur ^ 1][4 + dt] = *(const short8*)(vo + (size_t)dt * 16 * SS);
          }
        }
        const int hp = c * 4 + hp2;
        const unsigned int* wb = &Wc[hp * (16 * WROW) + l16 * WROW + quad * 8];
        const uint4 da = *(const uint4*)(wb);
        const uint4 db = *(const uint4*)(wb + 4);
        uint4 ue, uo;
        ue.x = (da.x & 0xffffu) | (da.y << 16);
        ue.y = (da.z & 0xffffu) | (da.w << 16);
        ue.z = (db.x & 0xffffu) | (db.y << 16);
        ue.w = (db.z & 0xffffu) | (db.w << 16);
        uo.x = (da.x >> 16) | (da.y & 0xffff0000u);
        uo.y = (da.z >> 16) | (da.w & 0xffff0000u);
        uo.z = (db.x >> 16) | (db.y & 0xffff0000u);
        uo.w = (db.z >> 16) | (db.w & 0xffff0000u);
        const short8 ae = __builtin_bit_cast(short8, ue);
        const short8 ao = __builtin_bit_cast(short8, uo);
        #pragma unroll
        for (int dt = 0; dt < 4; ++dt){
          O[hp2 * 2 + 0][dt] = __builtin_amdgcn_mfma_f32_16x16x32_bf16(ae, vb[cur][dt],     O[hp2 * 2 + 0][dt], 0, 0, 0);
          O[hp2 * 2 + 1][dt] = __builtin_amdgcn_mfma_f32_16x16x32_bf16(ao, vb[cur][4 + dt], O[hp2 * 2 + 1][dt], 0, 0, 0);
        }
      }
    }

    // ---- epilogue: atomic accumulate split-k partials (consumers only) ----
    #pragma unroll
    for (int j = 0; j < 8; ++j){
      const int h = c * 8 + j;
      #pragma unroll
      for (int dt = 0; dt < 4; ++dt){
        #pragma unroll
        for (int r = 0; r < 4; ++r){
          float* op = out + (((size_t)b * SS + (size_t)(q0 + quad * 4 + r)) * HH + h) * DD + dt * 16 + l16;
          unsafeAtomicAdd(op, O[j][dt][r]);
        }
      }
    }
  }
}

extern "C" void kernel_launch(void* const* d_in, const int* in_sizes, int n_in,
                              void* d_out, int out_size, void* d_ws, size_t ws_size,
                              hipStream_t stream)
{
  const float* Q = (const float*)d_in[0];
  const float* K = (const float*)d_in[1];
  const float* V = (const float*)d_in[2];
  const void* mask = d_in[3];

  uintptr_t base = (uintptr_t)d_ws;
  int* mode_ptr       = (int*)base;
  unsigned short* Qb  = (unsigned short*)(base + 64);
  unsigned short* Kb  = Qb + QE;
  unsigned short* Vt  = Kb + QE;
  unsigned short* pmp = Vt + QE;                 // 16.8 MB packed mask

  detect_mask_mode<<<1, 256, 0, stream>>>((const unsigned int*)mask, mode_ptr);
  pack_mask_kernel<<<(int)(PME / (256 * 8)), 256, 0, stream>>>(mask, mode_ptr, pmp);
  conv_bf16_kernel<<<2048, 256, 0, stream>>>(Q, Qb, 0.125f);
  conv_bf16_kernel<<<2048, 256, 0, stream>>>(K, Kb, 1.0f);
  transp_v_kernel<<<BB * HH * (SS / 64), 256, 0, stream>>>(V, Vt);
  hipMemsetAsync(d_out, 0, (size_t)out_size * sizeof(float), stream);

  attn_main_kernel<<<512, 256, 0, stream>>>(Qb, Kb, Vt, pmp, (float*)d_out);
}

// Round 9
// 990.629 us; speedup vs baseline: 1.1350x; 1.0270x over previous
//
#include <hip/hip_runtime.h>
#include <stdint.h>
#include <math.h>

// Problem constants: B=2, H=16, S=2048, D=64
#define BB 2
#define HH 16
#define SS 2048
#define DD 64
#define QE  ((size_t)BB * HH * SS * DD)  // elements per tensor
#define PME ((size_t)BB * SS * SS)       // packed-mask elements (uint16)

#define WROW 36                          // W row stride in DWORDS (32 + 4 pad)

typedef __attribute__((ext_vector_type(8))) short short8;   // bf16x8 MFMA frag
typedef __attribute__((ext_vector_type(4))) float float4v;  // fp32x4 accum

__device__ __forceinline__ float bflo(unsigned int u){ return __uint_as_float(u << 16); }
__device__ __forceinline__ float bfhi(unsigned int u){ return __uint_as_float(u & 0xffff0000u); }
__device__ __forceinline__ unsigned short f2bf(float f){
  unsigned int u = __float_as_uint(f);
  u += 0x7fffu + ((u >> 16) & 1u);   // RNE
  return (unsigned short)(u >> 16);
}
__device__ __forceinline__ unsigned int pk2(float lo, float hi){
  return ((unsigned int)f2bf(hi) << 16) | (unsigned int)f2bf(lo);
}

// ---------------------------------------------------------------------------
// Mask dtype detection (verified rounds 0-8).
// ---------------------------------------------------------------------------
__global__ void detect_mask_mode(const unsigned int* __restrict__ mw, int* __restrict__ mode_out){
  __shared__ int a32, af, a64;
  const int t = threadIdx.x;
  if (t == 0){ a32 = 1; af = 1; a64 = 1; }
  __syncthreads();
  int ok32 = 1, okf = 1, ok64 = 1;
  for (int idx = t; idx < 4096; idx += 256){
    const unsigned int w = mw[idx];
    if (w > 1u) ok32 = 0;
    if (w != 0u && w != 0x3F800000u) okf = 0;
    if ((idx & 1) ? (w != 0u) : (w > 1u)) ok64 = 0;
  }
  if (!ok32) atomicAnd(&a32, 0);
  if (!okf)  atomicAnd(&af, 0);
  if (!ok64) atomicAnd(&a64, 0);
  __syncthreads();
  if (t == 0){
    int mode;
    if (a64)      mode = 3;
    else if (a32) mode = 0;
    else if (af)  mode = 2;
    else          mode = 1;
    *mode_out = mode;
  }
}

// ---------------------------------------------------------------------------
// Pack mask[b][h][q][k] -> pm[b][q][k] uint16 (bit h set if masked).
// (verified round 3)
// ---------------------------------------------------------------------------
__global__ __launch_bounds__(256) void pack_mask_kernel(
    const void* __restrict__ mask, const int* __restrict__ modep,
    unsigned short* __restrict__ pm)
{
  const int mode = *modep;
  const size_t tid  = (size_t)blockIdx.x * 256 + threadIdx.x;
  const size_t base = tid * 8;
  const size_t bq   = base >> 11;
  const int    k0   = (int)(base & (SS - 1));
  const size_t b    = bq >> 11;
  const size_t q    = bq & (SS - 1);

  unsigned short outv[8] = {0,0,0,0,0,0,0,0};

  if (mode == 0 || mode == 2){
    const unsigned int* p = (const unsigned int*)mask;
    #pragma unroll
    for (int h = 0; h < HH; ++h){
      const size_t e = ((b * HH + h) * SS + q) * SS + k0;
      const uint4 a = *(const uint4*)(p + e);
      const uint4 c = *(const uint4*)(p + e + 4);
      const unsigned short bit = (unsigned short)(1u << h);
      if (a.x) outv[0] |= bit;  if (a.y) outv[1] |= bit;
      if (a.z) outv[2] |= bit;  if (a.w) outv[3] |= bit;
      if (c.x) outv[4] |= bit;  if (c.y) outv[5] |= bit;
      if (c.z) outv[6] |= bit;  if (c.w) outv[7] |= bit;
    }
  } else if (mode == 1){
    const unsigned char* p = (const unsigned char*)mask;
    #pragma unroll
    for (int h = 0; h < HH; ++h){
      const size_t e = ((b * HH + h) * SS + q) * SS + k0;
      uint2 a = *(const uint2*)(p + e);
      const unsigned short bit = (unsigned short)(1u << h);
      #pragma unroll
      for (int j = 0; j < 4; ++j){
        if ((a.x >> (8*j)) & 0xffu) outv[j]     |= bit;
        if ((a.y >> (8*j)) & 0xffu) outv[4 + j] |= bit;
      }
    }
  } else {
    const unsigned int* p = (const unsigned int*)mask;
    #pragma unroll
    for (int h = 0; h < HH; ++h){
      const size_t e = (((b * HH + h) * SS + q) * SS + k0) * 2;
      const unsigned short bit = (unsigned short)(1u << h);
      #pragma unroll
      for (int j = 0; j < 4; ++j){
        const uint4 a = *(const uint4*)(p + e + j * 4);
        if (a.x) outv[j * 2]     |= bit;
        if (a.z) outv[j * 2 + 1] |= bit;
      }
    }
  }

  uint4 w;
  w.x = (unsigned int)outv[0] | ((unsigned int)outv[1] << 16);
  w.y = (unsigned int)outv[2] | ((unsigned int)outv[3] << 16);
  w.z = (unsigned int)outv[4] | ((unsigned int)outv[5] << 16);
  w.w = (unsigned int)outv[6] | ((unsigned int)outv[7] << 16);
  *(uint4*)(pm + base) = w;
}

// ---------------------------------------------------------------------------
// Prep: fp32 -> bf16 (scale folded for Q)
// ---------------------------------------------------------------------------
__global__ void conv_bf16_kernel(const float* __restrict__ src, unsigned short* __restrict__ dst, float scale){
  const size_t i = ((size_t)blockIdx.x * 256 + threadIdx.x) * 8;
  const float4 a = *(const float4*)(src + i);
  const float4 b = *(const float4*)(src + i + 4);
  uint4 o;
  o.x = pk2(a.x * scale, a.y * scale);
  o.y = pk2(a.z * scale, a.w * scale);
  o.z = pk2(b.x * scale, b.y * scale);
  o.w = pk2(b.z * scale, b.w * scale);
  *(uint4*)(dst + i) = o;
}

// ---------------------------------------------------------------------------
// Prep: V[b,h,k,d] fp32 -> Vt[b,h,d,k] bf16 (verified round 1)
// ---------------------------------------------------------------------------
__global__ void transp_v_kernel(const float* __restrict__ V, unsigned short* __restrict__ Vt){
  __shared__ unsigned short tile[64][66];
  const int t  = threadIdx.x;
  const int kt = blockIdx.x & 31;
  const int bh = blockIdx.x >> 5;
  {
    const int kr = t >> 2, dc = (t & 3) * 16;
    const float* src = V + ((size_t)bh * SS + (size_t)(kt * 64 + kr)) * DD + dc;
    #pragma unroll
    for (int c = 0; c < 4; ++c){
      const float4 v = *(const float4*)(src + c * 4);
      tile[kr][dc + c * 4 + 0] = f2bf(v.x);
      tile[kr][dc + c * 4 + 1] = f2bf(v.y);
      tile[kr][dc + c * 4 + 2] = f2bf(v.z);
      tile[kr][dc + c * 4 + 3] = f2bf(v.w);
    }
  }
  __syncthreads();
  {
    const int dr = t >> 2, kc = (t & 3) * 16;
    unsigned short* dst = Vt + ((size_t)bh * DD + dr) * SS + kt * 64 + kc;
    unsigned int w[8];
    #pragma unroll
    for (int p = 0; p < 8; ++p){
      w[p] = (unsigned int)tile[kc + 2*p][dr] | ((unsigned int)tile[kc + 2*p + 1][dr] << 16);
    }
    uint4 o0 = { w[0], w[1], w[2], w[3] };
    uint4 o1 = { w[4], w[5], w[6], w[7] };
    *(uint4*)(dst)     = o0;
    *(uint4*)(dst + 8) = o1;
  }
}

// ---------------------------------------------------------------------------
// Main fused kernel — producer/consumer waves + CROSS-STEP K-LOAD PIPELINE.
// Block = 256 thr (4 waves). Waves 0-1 = producers, waves 2-3 = consumers.
// Round-8-verified structure; the ONE change this round is in the producer:
//  * K frags for the ENTIRE next step (16 heads x 2 frags = 128 VGPR) are
//    issued in ONE batch right after the current step's score MFMAs consume
//    the previous set. The ~3.5K-cycle softmax+write+barrier phase then
//    covers the full L2 latency -> zero exposed K-load latency in steady
//    state (vs 4 exposed latencies/step in round 8). Producers hold no O
//    accumulator, so the 128-reg K buffer fits (~200 VGPR total).
//  * Softmax -inf ternary replaced by one fmaxf(m,-1e30) clamp (identical
//    results incl. all-masked rows; exp(-inf)=0 natively).
// Consumer path and all layouts byte-identical to round 8 (verified).
// LDS: Qf 32 KB + Wp 2x18 KB = 68.6 KB -> 2 blocks/CU.
// ---------------------------------------------------------------------------
__global__ __launch_bounds__(256, 2) void attn_main_kernel(
    const unsigned short* __restrict__ Qb, const unsigned short* __restrict__ Kb,
    const unsigned short* __restrict__ Vt, const unsigned short* __restrict__ pm,
    float* __restrict__ out)
{
  __shared__ unsigned short Qf[HH * 2 * 512];     // 32768 B: [h][frag][lane*8]
  __shared__ unsigned int  Wp[2][8 * 16 * WROW];  // 2 x 18432 B

  const int t = threadIdx.x;
  const int wave = t >> 6, lane = t & 63, quad = lane >> 4, l16 = lane & 15;

  const int L  = blockIdx.x;
  const int b  = (L >> 1) & 1;
  const int kc = (L >> 2) & 1;
  const int q0 = (((L >> 3) << 1) | (L & 1)) * 16;

  // ---- stage Q A-frags to LDS once (wave w stages heads 4w..4w+3) ----
  #pragma unroll
  for (int hh = 0; hh < 4; ++hh){
    const int h = wave * 4 + hh;
    const unsigned short* qp = Qb + ((size_t)(b * HH + h) * SS + (size_t)(q0 + l16)) * DD + quad * 8;
    *(short8*)&Qf[(h * 2 + 0) * 512 + lane * 8] = *(const short8*)(qp);
    *(short8*)&Qf[(h * 2 + 1) * 512 + lane * 8] = *(const short8*)(qp + 32);
  }
  __syncthreads();

  if (wave < 2){
    // ======================= PRODUCER =======================
    const int p = wave;
    const unsigned short* kbas0 = Kb + ((size_t)(b * HH) * SS + (size_t)(kc * 1024 + p * 16 + l16)) * DD + quad * 8;
    const unsigned short* pmrow = pm + ((size_t)b * SS + (size_t)(q0 + quad * 4)) * SS + (size_t)(kc * 1024 + p * 16 + l16);

    unsigned int m16[4];
    #pragma unroll
    for (int r = 0; r < 4; ++r) m16[r] = (unsigned int)pmrow[(size_t)r * SS];

    // K frag buffer for one full step (16 heads x 2 frags = 128 VGPR)
    short8 kA[HH], kB[HH];
    {
      const unsigned short* kbase = kbas0;
      #pragma unroll
      for (int h = 0; h < HH; ++h){
        const unsigned short* kp = kbase + (size_t)h * (SS * DD);
        kA[h] = *(const short8*)(kp);
        kB[h] = *(const short8*)(kp + 32);
      }
    }

    #pragma unroll 1
    for (int ks = 0; ks < 32; ++ks){
      // ---- scores: all 16 heads; K frags already in flight/registers ----
      unsigned int sp[HH][2];
      #pragma unroll
      for (int h = 0; h < HH; ++h){
        const short8 a0 = *(const short8*)&Qf[(h * 2 + 0) * 512 + lane * 8];
        const short8 a1 = *(const short8*)&Qf[(h * 2 + 1) * 512 + lane * 8];
        float4v c = (float4v){0.f, 0.f, 0.f, 0.f};
        c = __builtin_amdgcn_mfma_f32_16x16x32_bf16(a0, kA[h], c, 0, 0, 0);
        c = __builtin_amdgcn_mfma_f32_16x16x32_bf16(a1, kB[h], c, 0, 0, 0);
        #pragma unroll
        for (int r = 0; r < 4; ++r) if ((m16[r] >> h) & 1u) c[r] = -INFINITY;
        sp[h][0] = pk2(c[0], c[1]);
        sp[h][1] = pk2(c[2], c[3]);
      }

      // ---- issue ALL K loads for step ks+1 (latency hidden by softmax) ----
      if (ks < 31){
        const unsigned short* kbase = kbas0 + (size_t)(ks + 1) * 32 * DD;
        #pragma unroll
        for (int h = 0; h < HH; ++h){
          const unsigned short* kp = kbase + (size_t)h * (SS * DD);
          kA[h] = *(const short8*)(kp);
          kB[h] = *(const short8*)(kp + 32);
        }
        // next step's mask words too
        #pragma unroll
        for (int r = 0; r < 4; ++r) m16[r] = (unsigned int)pmrow[(size_t)r * SS + (size_t)(ks + 1) * 32];
      }

      // ---- in-lane softmax over heads; packed head-pair dword writes ----
      unsigned int* Wc = &Wp[ks & 1][0];
      const int kdx = p * 16 + l16;
      #pragma unroll
      for (int r = 0; r < 4; ++r){
        const int row = quad * 4 + r;
        float sv[HH];
        float m = -INFINITY;
        #pragma unroll
        for (int h = 0; h < HH; ++h){
          const unsigned int u = sp[h][r >> 1];
          const float f = (r & 1) ? bfhi(u) : bflo(u);
          sv[h] = f;
          m = fmaxf(m, f);
        }
        m = fmaxf(m, -1e30f);            // all-masked row -> exp(-inf+1e30)=0, rinv=0
        float sum = 0.f;
        #pragma unroll
        for (int h = 0; h < HH; ++h){
          const float e = __expf(sv[h] - m);   // exp(-inf)=0 natively for masked h
          sv[h] = e;
          sum += e;
        }
        const float rinv = (sum > 0.f) ? (1.0f / sum) : 0.f;
        #pragma unroll
        for (int hp = 0; hp < 8; ++hp){
          Wc[hp * (16 * WROW) + row * WROW + kdx] = pk2(sv[2 * hp] * rinv, sv[2 * hp + 1] * rinv);
        }
      }
      __syncthreads();
    }
  } else {
    // ======================= CONSUMER (round-8-verified, unchanged) =======================
    const int c = wave - 2;                 // owns heads 8c..8c+7 (hp 4c..4c+3)
    float4v O[8][4];                        // [head j = 2*hp2+parity][d-tile]
    #pragma unroll
    for (int i = 0; i < 8; ++i)
      #pragma unroll
      for (int j = 0; j < 4; ++j) O[i][j] = (float4v){0.f, 0.f, 0.f, 0.f};

    #pragma unroll 1
    for (int ks = 0; ks < 32; ++ks){
      const int k0 = kc * 1024 + ks * 32;

      // ---- Vt prefetch for hp2=0 BEFORE the barrier (independent of W) ----
      short8 vb[2][8];   // [buf][head-even dt0..3, head-odd dt0..3]
      {
        const int hp = c * 4;
        const unsigned short* ve = Vt + ((size_t)(b * HH + 2 * hp) * DD + l16) * SS + k0 + quad * 8;
        const unsigned short* vo = ve + (size_t)SS * DD;
        #pragma unroll
        for (int dt = 0; dt < 4; ++dt){
          vb[0][dt]     = *(const short8*)(ve + (size_t)dt * 16 * SS);
          vb[0][4 + dt] = *(const short8*)(vo + (size_t)dt * 16 * SS);
        }
      }
      __syncthreads();

      const unsigned int* Wc = &Wp[ks & 1][0];
      #pragma unroll
      for (int hp2 = 0; hp2 < 4; ++hp2){
        const int cur = hp2 & 1;
        if (hp2 < 3){
          const int hpn = c * 4 + hp2 + 1;
          const unsigned short* ve = Vt + ((size_t)(b * HH + 2 * hpn) * DD + l16) * SS + k0 + quad * 8;
          const unsigned short* vo = ve + (size_t)SS * DD;
          #pragma unroll
          for (int dt = 0; dt < 4; ++dt){
            vb[cur ^ 1][dt]     = *(const short8*)(ve + (size_t)dt * 16 * SS);
            vb[cur ^ 1][4 + dt] = *(const short8*)(vo + (size_t)dt * 16 * SS);
          }
        }
        const int hp = c * 4 + hp2;
        const unsigned int* wb = &Wc[hp * (16 * WROW) + l16 * WROW + quad * 8];
        const uint4 da = *(const uint4*)(wb);
        const uint4 db = *(const uint4*)(wb + 4);
        uint4 ue, uo;
        ue.x = (da.x & 0xffffu) | (da.y << 16);
        ue.y = (da.z & 0xffffu) | (da.w << 16);
        ue.z = (db.x & 0xffffu) | (db.y << 16);
        ue.w = (db.z & 0xffffu) | (db.w << 16);
        uo.x = (da.x >> 16) | (da.y & 0xffff0000u);
        uo.y = (da.z >> 16) | (da.w & 0xffff0000u);
        uo.z = (db.x >> 16) | (db.y & 0xffff0000u);
        uo.w = (db.z >> 16) | (db.w & 0xffff0000u);
        const short8 ae = __builtin_bit_cast(short8, ue);
        const short8 ao = __builtin_bit_cast(short8, uo);
        #pragma unroll
        for (int dt = 0; dt < 4; ++dt){
          O[hp2 * 2 + 0][dt] = __builtin_amdgcn_mfma_f32_16x16x32_bf16(ae, vb[cur][dt],     O[hp2 * 2 + 0][dt], 0, 0, 0);
          O[hp2 * 2 + 1][dt] = __builtin_amdgcn_mfma_f32_16x16x32_bf16(ao, vb[cur][4 + dt], O[hp2 * 2 + 1][dt], 0, 0, 0);
        }
      }
    }

    // ---- epilogue: atomic accumulate split-k partials (consumers only) ----
    #pragma unroll
    for (int j = 0; j < 8; ++j){
      const int h = c * 8 + j;
      #pragma unroll
      for (int dt = 0; dt < 4; ++dt){
        #pragma unroll
        for (int r = 0; r < 4; ++r){
          float* op = out + (((size_t)b * SS + (size_t)(q0 + quad * 4 + r)) * HH + h) * DD + dt * 16 + l16;
          unsafeAtomicAdd(op, O[j][dt][r]);
        }
      }
    }
  }
}

extern "C" void kernel_launch(void* const* d_in, const int* in_sizes, int n_in,
                              void* d_out, int out_size, void* d_ws, size_t ws_size,
                              hipStream_t stream)
{
  const float* Q = (const float*)d_in[0];
  const float* K = (const float*)d_in[1];
  const float* V = (const float*)d_in[2];
  const void* mask = d_in[3];

  uintptr_t base = (uintptr_t)d_ws;
  int* mode_ptr       = (int*)base;
  unsigned short* Qb  = (unsigned short*)(base + 64);
  unsigned short* Kb  = Qb + QE;
  unsigned short* Vt  = Kb + QE;
  unsigned short* pmp = Vt + QE;                 // 16.8 MB packed mask

  detect_mask_mode<<<1, 256, 0, stream>>>((const unsigned int*)mask, mode_ptr);
  pack_mask_kernel<<<(int)(PME / (256 * 8)), 256, 0, stream>>>(mask, mode_ptr, pmp);
  conv_bf16_kernel<<<2048, 256, 0, stream>>>(Q, Qb, 0.125f);
  conv_bf16_kernel<<<2048, 256, 0, stream>>>(K, Kb, 1.0f);
  transp_v_kernel<<<BB * HH * (SS / 64), 256, 0, stream>>>(V, Vt);
  hipMemsetAsync(d_out, 0, (size_t)out_size * sizeof(float), stream);

  attn_main_kernel<<<512, 256, 0, stream>>>(Qb, Kb, Vt, pmp, (float*)d_out);
}